// Round 2
// baseline (21363.832 us; speedup 1.0000x reference)
//
#include <hip/hip_runtime.h>
#include <math.h>

#define T_ 128
#define B_ 256
#define D_ 128
#define L_ 32
#define C_ 64
#define H_ 256
#define S_ 16
#define R_ 4096   // S*B
#define NT_ 127
#define DT 0.02f
#define SQDT 0.14142135623730951f

__device__ __forceinline__ float sp_(float x){
  return fmaxf(x, 0.f) + __logf(1.f + __expf(-fabsf(x)));
}
__device__ __forceinline__ float sig_(float x){
  return 1.f / (1.f + __expf(-x));
}
__device__ __forceinline__ float tanh_(float x){
  return 1.f - 2.f / (1.f + __expf(2.f * x));
}

// block of 256 threads -> one double atomicAdd
__device__ __forceinline__ void blk_reduce_add(float v, double* acc){
  for (int o = 32; o > 0; o >>= 1) v += __shfl_down(v, o, 64);
  __shared__ float wpart[4];
  int lane = threadIdx.x & 63, w = threadIdx.x >> 6;
  if (lane == 0) wpart[w] = v;
  __syncthreads();
  if (threadIdx.x == 0) atomicAdd(acc, (double)(wpart[0] + wpart[1] + wpart[2] + wpart[3]));
}

__global__ void k_init(double* accs){ if (threadIdx.x < 3) accs[threadIdx.x] = 0.0; }

// xT[t][d][b] = xs_pre[b][t][d]
__global__ void k_tx(const float* __restrict__ xs_pre, float* __restrict__ xT){
  int i = blockIdx.x * 256 + threadIdx.x;
  int b = i & 255; int d = (i >> 8) & 127; int t = i >> 15;
  xT[i] = xs_pre[(b * T_ + t) * D_ + d];
}

// g-weights transposed to [h][l]
__global__ void k_tsmall(const float* __restrict__ gW1, const float* __restrict__ gb1,
                         const float* __restrict__ gW2,
                         float* __restrict__ gW1T, float* __restrict__ gb1T,
                         float* __restrict__ gW2T){
  int i = blockIdx.x * 256 + threadIdx.x;
  int sec = i >> 13, idx = i & 8191;
  int h = idx >> 5, l = idx & 31;
  if (sec == 0) gW1T[idx] = gW1[l * H_ + h];
  else if (sec == 1) gb1T[idx] = gb1[l * H_ + h];
  else gW2T[idx] = gW2[l * H_ + h];
}

// GRU step k, 4-way split-K over the 384 (128 x + 256 h) reduction columns.
// block = jj (256 blocks), 1024 threads: b = tid&255, ks = tid>>8.
__global__ __launch_bounds__(1024) void k_gru(
    const float* __restrict__ xT, const float* __restrict__ Wih,
    const float* __restrict__ Whh, const float* __restrict__ bih,
    const float* __restrict__ bhh, float* __restrict__ hsT, int k){
  int jj = blockIdx.x;
  int b = threadIdx.x & 255;
  int ks = threadIdx.x >> 8;
  int t = 127 - k;
  const float* xcol = xT + t * D_ * B_ + b;
  const float* wr = Wih + jj * D_;
  const float* wz = wr + H_ * D_;
  const float* wn = wz + H_ * D_;
  const float* hrow = hsT + (k - 1) * H_ * B_ + b;  // valid only k>0
  const float* vr = Whh + jj * H_;
  const float* vz = vr + H_ * H_;
  const float* vn = vz + H_ * H_;
  float ar = 0.f, az = 0.f, anx = 0.f, anh = 0.f;
  // x part: u in [ks*96, min(ks*96+96, 128))
  int xs0 = ks * 96; int xe = xs0 + 96; if (xe > 128) xe = 128;
  #pragma unroll 8
  for (int u = xs0; u < xe; ++u){
    float v = xcol[u * B_];
    ar = fmaf(v, wr[u], ar);
    az = fmaf(v, wz[u], az);
    anx = fmaf(v, wn[u], anx);
  }
  if (k > 0){
    int hs = ks * 96 - 128; if (hs < 0) hs = 0;
    int he = ks * 96 + 96 - 128;
    #pragma unroll 8
    for (int q = hs; q < he; ++q){
      float v = hrow[q * B_];
      ar = fmaf(v, vr[q], ar);
      az = fmaf(v, vz[q], az);
      anh = fmaf(v, vn[q], anh);
    }
  }
  __shared__ float part[4][3][256];
  if (ks > 0){
    part[0][ks - 1][b] = ar;
    part[1][ks - 1][b] = az;
    part[2][ks - 1][b] = anx + anh;   // anx is 0 for ks>=2; keep split only for ks0
  }
  // careful: n-gate needs x and h parts separate. ks0 has only-x anh==0 for its range?
  // ks0 covers u<96 (x only) -> anh=0. ks1 covers x 96..127 and h 0..63 -> has both!
  __shared__ float partnh[4][256];
  if (ks > 0) partnh[ks - 1][b] = anh;
  __syncthreads();
  if (ks == 0){
    float gr = ar + part[0][0][b] + part[0][1][b] + part[0][2][b] + bih[jj] + bhh[jj];
    float gz = az + part[1][0][b] + part[1][1][b] + part[1][2][b] + bih[jj + H_] + bhh[jj + H_];
    float sum_nh = anh + partnh[0][b] + partnh[1][b] + partnh[2][b];
    float sum_all = anx + anh + part[2][0][b] + part[2][1][b] + part[2][2][b];
    float gin = (sum_all - sum_nh) + bih[jj + 2 * H_];
    float ghn = sum_nh + bhh[jj + 2 * H_];
    float hprev = (k > 0) ? hrow[jj * B_] : 0.f;
    float r = sig_(gr);
    float u = sig_(gz);
    float n = tanh_(gin + r * ghn);
    hsT[k * H_ * B_ + jj * B_ + b] = (1.f - u) * n + u * hprev;
  }
}

// ctxT[t][c][b] = hs[127-t] @ encW^T + encb
__global__ void k_ctx(const float* __restrict__ hsT, const float* __restrict__ encW,
                      const float* __restrict__ encb, float* __restrict__ ctxT){
  int b = threadIdx.x;
  int c = blockIdx.x & 63;
  int t = blockIdx.x >> 6;
  const float* hrow = hsT + (127 - t) * H_ * B_ + b;
  const float* w = encW + c * H_;
  float acc = encb[c];
  #pragma unroll 8
  for (int q = 0; q < H_; ++q) acc = fmaf(hrow[q * B_], w[q], acc);
  ctxT[(t * C_ + c) * B_ + b] = acc;
}

// q(z0) head + KL(q||p) reduction
__global__ void k_qz0(const float* __restrict__ ctxT, const float* __restrict__ qW,
                      const float* __restrict__ qb, const float* __restrict__ pm,
                      const float* __restrict__ pls, float* __restrict__ qmT,
                      float* __restrict__ qlsT, double* __restrict__ kl_acc){
  int b = threadIdx.x; int l = blockIdx.x;
  const float* crow = ctxT + b;  // ctxT[0][c][b]
  const float* wm = qW + l * C_;
  const float* ws2 = qW + (L_ + l) * C_;
  float am = qb[l], as = qb[L_ + l];
  for (int c = 0; c < C_; ++c){
    float cv = crow[c * B_];
    am = fmaf(cv, wm[c], am);
    as = fmaf(cv, ws2[c], as);
  }
  qmT[l * B_ + b] = am; qlsT[l * B_ + b] = as;
  float plsl = pls[l], pml = pm[l];
  float dm = am - pml;
  float kl = plsl - as + (__expf(2.f * as) + dm * dm) / (2.f * __expf(2.f * plsl)) - 0.5f;
  blk_reduce_add(kl, kl_acc);
}

// z0 = qm + exp(qls)*eps0 ; write z0T and zs_t[:, :, 0, :]
__global__ void k_z0(const float* __restrict__ eps0, const float* __restrict__ qmT,
                     const float* __restrict__ qlsT, float* __restrict__ z0T,
                     float* __restrict__ zs){
  int r = blockIdx.x * 256 + threadIdx.x;
  int b = r & 255;
  for (int l = 0; l < L_; ++l){
    float z = fmaf(__expf(qlsT[l * B_ + b]), eps0[r * L_ + l], qmT[l * B_ + b]);
    z0T[l * R_ + r] = z;
    zs[r * T_ * L_ + l] = z;
  }
}

#define JC1 16
// layer 1 of f (K=96: 32 z + 64 ctx) and h (K=32), 2-way split-K, 512 threads.
__global__ __launch_bounds__(512) void k_l1(
    const float* __restrict__ zT, const float* __restrict__ ctxT,
    const float* __restrict__ fW1, const float* __restrict__ fb1,
    const float* __restrict__ hW1, const float* __restrict__ hb1,
    float* __restrict__ ab1T, int tctx){
  int b = threadIdx.x & 255;
  int ks = threadIdx.x >> 8;
  int rb = blockIdx.x & 15; int jg = blockIdx.x >> 4;  // 0..31
  int r = rb * 256 + b;
  int j0 = jg * JC1;
  float acc[JC1];
  #pragma unroll
  for (int q = 0; q < JC1; ++q) acc[q] = 0.f;
  if (j0 < H_){
    const float* wbase = fW1 + j0 * 96;
    // unified col u in [0,96): u<32 -> z, else ctx (weight col index == u)
    int u0 = ks * 48, u1 = u0 + 48;
    int ze = u1 < 32 ? u1 : 32;
    const float* crow = ctxT + tctx * C_ * B_ + b;
    for (int u = u0; u < ze; ++u){
      float v = zT[u * R_ + r];
      #pragma unroll
      for (int q = 0; q < JC1; ++q) acc[q] = fmaf(v, wbase[q * 96 + u], acc[q]);
    }
    int cs = u0 > 32 ? u0 : 32;
    for (int u = cs; u < u1; ++u){
      float v = crow[(u - 32) * B_];
      #pragma unroll
      for (int q = 0; q < JC1; ++q) acc[q] = fmaf(v, wbase[q * 96 + u], acc[q]);
    }
  } else {
    const float* wbase = hW1 + (j0 - H_) * L_;
    int u0 = ks * 16, u1 = u0 + 16;
    for (int u = u0; u < u1; ++u){
      float v = zT[u * R_ + r];
      #pragma unroll
      for (int q = 0; q < JC1; ++q) acc[q] = fmaf(v, wbase[q * L_ + u], acc[q]);
    }
  }
  __shared__ float lds[JC1][256];
  if (ks == 1){
    #pragma unroll
    for (int q = 0; q < JC1; ++q) lds[q][b] = acc[q];
  }
  __syncthreads();
  if (ks == 0){
    const float* bb = (j0 < H_) ? (fb1 + j0) : (hb1 + (j0 - H_));
    #pragma unroll
    for (int q = 0; q < JC1; ++q)
      ab1T[(j0 + q) * R_ + r] = sp_(acc[q] + lds[q][b] + bb[q]);
  }
}

#define JC2 32
// layer 2 of f and h (256x256 each); JC=32, 4-way split-K, 1024 threads.
__global__ __launch_bounds__(1024) void k_l2(
    const float* __restrict__ ab1T, const float* __restrict__ fW2,
    const float* __restrict__ fb2, const float* __restrict__ hW2,
    const float* __restrict__ hb2, float* __restrict__ ab2T){
  int b = threadIdx.x & 255;
  int ks = threadIdx.x >> 8;
  int rb = blockIdx.x & 15; int jg = blockIdx.x >> 4;  // 0..15
  int r = rb * 256 + b;
  int j0 = jg * JC2;
  const float* in; const float* w; const float* bb;
  if (j0 < H_){ in = ab1T;            w = fW2 + j0 * H_;        bb = fb2 + j0; }
  else        { in = ab1T + H_ * R_;  w = hW2 + (j0 - H_) * H_; bb = hb2 + (j0 - H_); }
  float acc[JC2];
  #pragma unroll
  for (int q = 0; q < JC2; ++q) acc[q] = 0.f;
  for (int kk = ks * 64; kk < ks * 64 + 64; ++kk){
    float v = in[kk * R_ + r];
    #pragma unroll
    for (int q = 0; q < JC2; ++q) acc[q] = fmaf(v, w[q * H_ + kk], acc[q]);
  }
  __shared__ float lds[JC2][256];   // 32 KB, sequenced combine
  if (ks == 2){
    #pragma unroll
    for (int q = 0; q < JC2; ++q) lds[q][b] = acc[q];
  }
  __syncthreads();
  if (ks == 3){
    #pragma unroll
    for (int q = 0; q < JC2; ++q) lds[q][b] += acc[q];
  }
  __syncthreads();
  if (ks == 1){
    #pragma unroll
    for (int q = 0; q < JC2; ++q) lds[q][b] += acc[q];
  }
  __syncthreads();
  if (ks == 0){
    #pragma unroll
    for (int q = 0; q < JC2; ++q)
      ab2T[(j0 + q) * R_ + r] = sp_(acc[q] + lds[q][b] + bb[q]);
  }
}

#define JC3 8
// layer 3: fv (j<32), hv (j>=32) -> fhT[j][r]; 4-way split-K, 1024 threads.
__global__ __launch_bounds__(1024) void k_l3(
    const float* __restrict__ ab2T, const float* __restrict__ fW3,
    const float* __restrict__ fb3, const float* __restrict__ hW3,
    const float* __restrict__ hb3, float* __restrict__ fhT){
  int b = threadIdx.x & 255;
  int ks = threadIdx.x >> 8;
  int rb = blockIdx.x & 15; int jg = blockIdx.x >> 4;  // 0..7
  int r = rb * 256 + b;
  int j0 = jg * JC3;
  const float* in; const float* w; const float* bb;
  if (j0 < L_){ in = ab2T;           w = fW3 + j0 * H_;        bb = fb3 + j0; }
  else        { in = ab2T + H_ * R_; w = hW3 + (j0 - L_) * H_; bb = hb3 + (j0 - L_); }
  float acc[JC3];
  #pragma unroll
  for (int q = 0; q < JC3; ++q) acc[q] = 0.f;
  for (int kk = ks * 64; kk < ks * 64 + 64; ++kk){
    float v = in[kk * R_ + r];
    #pragma unroll
    for (int q = 0; q < JC3; ++q) acc[q] = fmaf(v, w[q * H_ + kk], acc[q]);
  }
  __shared__ float lds[3][JC3][256];  // 24 KB
  if (ks > 0){
    #pragma unroll
    for (int q = 0; q < JC3; ++q) lds[ks - 1][q][b] = acc[q];
  }
  __syncthreads();
  if (ks == 0){
    #pragma unroll
    for (int q = 0; q < JC3; ++q)
      fhT[(j0 + q) * R_ + r] = acc[q] + lds[0][q][b] + lds[1][q][b] + lds[2][q][b] + bb[q];
  }
}

// diagonal g-net + euler update + logqp accumulation
__global__ void k_gu(const float* __restrict__ zT, const float* __restrict__ fhT,
                     const float* __restrict__ gW1T, const float* __restrict__ gb1T,
                     const float* __restrict__ gW2T, const float* __restrict__ gb2,
                     const float* __restrict__ dW, float* __restrict__ znT,
                     float* __restrict__ zs, double* __restrict__ u2_acc, int k){
  int l = threadIdx.x & 31; int rg = threadIdx.x >> 5;
  int r = blockIdx.x * 8 + rg;
  float zl = zT[l * R_ + r];
  float gacc = 0.f;
  #pragma unroll 4
  for (int h = 0; h < H_; ++h){
    float x = fmaf(zl, gW1T[h * L_ + l], gb1T[h * L_ + l]);
    gacc = fmaf(sp_(x), gW2T[h * L_ + l], gacc);
  }
  float gv = sig_(gacc + gb2[l]) + 0.01f;
  float fv = fhT[l * R_ + r];
  float hv = fhT[(L_ + l) * R_ + r];
  float u = (fv - hv) / gv;
  blk_reduce_add(u * u, u2_acc);
  float dwv = dW[k * (S_ * B_ * L_) + r * L_ + l];
  float zn = zl + fv * DT + gv * (SQDT * dwv);
  znT[l * R_ + r] = zn;
  zs[(r * T_ + (k + 1)) * L_ + l] = zn;
}

// Poisson log-likelihood: grid-stride, one atomic per block
__global__ void k_pois(const float* __restrict__ zs, const float* __restrict__ Cw,
                       const float* __restrict__ db, const float* __restrict__ xs_pre,
                       double* __restrict__ ell_acc){
  const int N = S_ * B_ * T_ * D_;           // 67,108,864
  const int stride = 4096 * 256;
  float local = 0.f;
  for (int i = blockIdx.x * 256 + threadIdx.x; i < N; i += stride){
    int d = i & 127; int row = i >> 7;       // row = (s*B + b)*T + t
    int t = row & 127; int b = (row >> 7) & 255;
    const float* zrow = zs + (size_t)row * L_;
    float lr = db[d] - 3.912023005428146f;   // + log(0.02)
    #pragma unroll 8
    for (int l = 0; l < L_; ++l) lr = fmaf(zrow[l], Cw[l * D_ + d], lr);
    float xv = xs_pre[(b * T_ + t) * D_ + d];
    int xi = (int)(xv + 0.5f);
    float lg = (xi <= 1) ? 0.f : (xi == 2 ? 0.6931471805599453f :
               (xi == 3 ? 1.791759469228055f : 3.1780538303479458f));
    local += xv * lr - __expf(lr) - lg;
  }
  blk_reduce_add(local, ell_acc);
}

// mean and unbiased variance over S
__global__ void k_mv(const float* __restrict__ zs, float* __restrict__ m, float* __restrict__ P){
  int i = blockIdx.x * 256 + threadIdx.x;   // (b,t,l) flat
  float x[S_];
  float s = 0.f;
  #pragma unroll
  for (int q = 0; q < S_; ++q){ x[q] = zs[q * (B_ * T_ * L_) + i]; s += x[q]; }
  float mu = s * (1.f / S_);
  float v = 0.f;
  #pragma unroll
  for (int q = 0; q < S_; ++q){ float dd = x[q] - mu; v = fmaf(dd, dd, v); }
  m[i] = mu;
  P[i] = v * (1.f / (S_ - 1));
}

__global__ void k_fin(const double* __restrict__ accs, float* __restrict__ out){
  double log_pxs = accs[0] / 4096.0;
  double logqp0 = accs[1] / 256.0;
  double logqp_path = 0.5 * 0.02 * accs[2] / 4096.0;
  out[0] = (float)(-log_pxs + logqp0 + logqp_path);
}

extern "C" void kernel_launch(void* const* d_in, const int* in_sizes, int n_in,
                              void* d_out, int out_size, void* d_ws, size_t ws_size,
                              hipStream_t stream) {
  const float* xs_pre = (const float*)d_in[0];
  const float* eps0   = (const float*)d_in[1];
  const float* dW     = (const float*)d_in[2];
  const float* Wih    = (const float*)d_in[3];
  const float* Whh    = (const float*)d_in[4];
  const float* bih    = (const float*)d_in[5];
  const float* bhh    = (const float*)d_in[6];
  const float* encW   = (const float*)d_in[7];
  const float* encb   = (const float*)d_in[8];
  const float* qW     = (const float*)d_in[9];
  const float* qb     = (const float*)d_in[10];
  const float* fW1    = (const float*)d_in[11];
  const float* fb1    = (const float*)d_in[12];
  const float* fW2    = (const float*)d_in[13];
  const float* fb2    = (const float*)d_in[14];
  const float* fW3    = (const float*)d_in[15];
  const float* fb3    = (const float*)d_in[16];
  const float* hW1    = (const float*)d_in[17];
  const float* hb1    = (const float*)d_in[18];
  const float* hW2    = (const float*)d_in[19];
  const float* hb2    = (const float*)d_in[20];
  const float* hW3    = (const float*)d_in[21];
  const float* hb3    = (const float*)d_in[22];
  const float* gW1    = (const float*)d_in[23];
  const float* gb1    = (const float*)d_in[24];
  const float* gW2    = (const float*)d_in[25];
  const float* gb2    = (const float*)d_in[26];
  const float* pm     = (const float*)d_in[27];
  const float* pls    = (const float*)d_in[28];
  const float* Cw     = (const float*)d_in[29];
  const float* db     = (const float*)d_in[30];

  float* out = (float*)d_out;
  float* zs  = out + 1;                      // (S,B,T,L)
  float* m   = out + 1 + 16777216;           // (B,T,L)
  float* P   = m + 1048576;

  // workspace layout
  double* accs = (double*)d_ws;              // [0]=ell, [1]=kl, [2]=u2
  float* wf = (float*)d_ws + 16;
  float* xT   = wf; wf += T_ * D_ * B_;      // 4,194,304
  float* hsT  = wf; wf += T_ * H_ * B_;      // 8,388,608
  float* ctxT = wf; wf += T_ * C_ * B_;      // 2,097,152
  float* zbuf = wf; wf += 2 * L_ * R_;       // 262,144
  float* ab1T = wf; wf += 2 * H_ * R_;       // 2,097,152
  float* ab2T = wf; wf += 2 * H_ * R_;       // 2,097,152
  float* fhT  = wf; wf += 2 * L_ * R_;       // 262,144
  float* qmT  = wf; wf += L_ * B_;
  float* qlsT = wf; wf += L_ * B_;
  float* gW1T = wf; wf += 8192;
  float* gb1T = wf; wf += 8192;
  float* gW2T = wf; wf += 8192;
  size_t need = (size_t)(wf - (float*)d_ws) * 4;
  if (ws_size < need) return;  // workspace too small: fail loudly

  k_init<<<1, 64, 0, stream>>>(accs);
  k_tx<<<16384, 256, 0, stream>>>(xs_pre, xT);
  k_tsmall<<<96, 256, 0, stream>>>(gW1, gb1, gW2, gW1T, gb1T, gW2T);

  for (int k = 0; k < T_; ++k)
    k_gru<<<256, 1024, 0, stream>>>(xT, Wih, Whh, bih, bhh, hsT, k);

  k_ctx<<<8192, 256, 0, stream>>>(hsT, encW, encb, ctxT);
  k_qz0<<<32, 256, 0, stream>>>(ctxT, qW, qb, pm, pls, qmT, qlsT, accs + 1);
  k_z0<<<16, 256, 0, stream>>>(eps0, qmT, qlsT, zbuf, zs);

  for (int k = 0; k < NT_; ++k){
    float* zc = zbuf + (k & 1) * (L_ * R_);
    float* zn = zbuf + ((k + 1) & 1) * (L_ * R_);
    int tctx = (k + 1 < T_ - 1) ? (k + 1) : (T_ - 1);
    k_l1<<<512, 512, 0, stream>>>(zc, ctxT, fW1, fb1, hW1, hb1, ab1T, tctx);
    k_l2<<<256, 1024, 0, stream>>>(ab1T, fW2, fb2, hW2, hb2, ab2T);
    k_l3<<<128, 1024, 0, stream>>>(ab2T, fW3, fb3, hW3, hb3, fhT);
    k_gu<<<512, 256, 0, stream>>>(zc, fhT, gW1T, gb1T, gW2T, gb2, dW, zn, zs, accs + 2, k);
  }

  k_pois<<<4096, 256, 0, stream>>>(zs, Cw, db, xs_pre, accs + 0);
  k_mv<<<4096, 256, 0, stream>>>(zs, m, P);
  k_fin<<<1, 1, 0, stream>>>(accs, out);
}

// Round 3
// 12989.896 us; speedup vs baseline: 1.6447x; 1.6447x over previous
//
#include <hip/hip_runtime.h>
#include <math.h>

#define T_ 128
#define B_ 256
#define D_ 128
#define L_ 32
#define C_ 64
#define H_ 256
#define S_ 16
#define R_ 4096   // S*B
#define NT_ 127
#define DT 0.02f
#define SQDT 0.14142135623730951f

__device__ __forceinline__ float sp_(float x){
  return fmaxf(x, 0.f) + __logf(1.f + __expf(-fabsf(x)));
}
__device__ __forceinline__ float sig_(float x){
  return 1.f / (1.f + __expf(-x));
}
__device__ __forceinline__ float tanh_(float x){
  return 1.f - 2.f / (1.f + __expf(2.f * x));
}

// 256-thread block -> one double atomicAdd
__device__ __forceinline__ void blk_reduce_add(float v, double* acc){
  for (int o = 32; o > 0; o >>= 1) v += __shfl_down(v, o, 64);
  __shared__ float wpart[4];
  int lane = threadIdx.x & 63, w = threadIdx.x >> 6;
  if (lane == 0) wpart[w] = v;
  __syncthreads();
  if (threadIdx.x == 0) atomicAdd(acc, (double)(wpart[0] + wpart[1] + wpart[2] + wpart[3]));
}

__global__ void k_init(double* accs){ if (threadIdx.x < 3) accs[threadIdx.x] = 0.0; }

// all weight transposes, one grid-stride kernel (516,096 elements)
__global__ void k_prep(const float* __restrict__ Wih, const float* __restrict__ Whh,
                       const float* __restrict__ encW,
                       const float* __restrict__ fW1, const float* __restrict__ hW1,
                       const float* __restrict__ fW2, const float* __restrict__ hW2,
                       const float* __restrict__ fW3, const float* __restrict__ hW3,
                       const float* __restrict__ gW1, const float* __restrict__ gb1,
                       const float* __restrict__ gW2,
                       float* WihT, float* WhhT, float* encWT,
                       float* fW1T, float* hW1T, float* fW2T, float* hW2T,
                       float* fW3T, float* hW3T,
                       float* gW1T, float* gb1T, float* gW2T){
  int i = blockIdx.x * 256 + threadIdx.x;
  if (i < 98304){ int d = i / 768, j = i % 768; WihT[i] = Wih[j*128 + d]; return; }
  i -= 98304;
  if (i < 196608){ int k2 = i / 768, j = i % 768; WhhT[i] = Whh[j*256 + k2]; return; }
  i -= 196608;
  if (i < 16384){ int k2 = i >> 6, c = i & 63; encWT[i] = encW[c*256 + k2]; return; }
  i -= 16384;
  if (i < 24576){ int k2 = i >> 8, j = i & 255; fW1T[i] = fW1[j*96 + k2]; return; }
  i -= 24576;
  if (i < 8192){ int k2 = i >> 8, j = i & 255; hW1T[i] = hW1[j*32 + k2]; return; }
  i -= 8192;
  if (i < 65536){ int k2 = i >> 8, j = i & 255; fW2T[i] = fW2[j*256 + k2]; return; }
  i -= 65536;
  if (i < 65536){ int k2 = i >> 8, j = i & 255; hW2T[i] = hW2[j*256 + k2]; return; }
  i -= 65536;
  if (i < 8192){ int k2 = i >> 5, j = i & 31; fW3T[i] = fW3[j*256 + k2]; return; }
  i -= 8192;
  if (i < 8192){ int k2 = i >> 5, j = i & 31; hW3T[i] = hW3[j*256 + k2]; return; }
  i -= 8192;
  if (i < 8192){ int h = i >> 5, l = i & 31; gW1T[i] = gW1[l*256 + h]; return; }
  i -= 8192;
  if (i < 8192){ int h = i >> 5, l = i & 31; gb1T[i] = gb1[l*256 + h]; return; }
  i -= 8192;
  if (i < 8192){ int h = i >> 5, l = i & 31; gW2T[i] = gW2[l*256 + h]; return; }
}

// xG[t][b][d] = xs_pre[b][t][d]
__global__ void k_xg(const float* __restrict__ xs_pre, float* __restrict__ xG){
  int i = blockIdx.x * 256 + threadIdx.x;
  int d = i & 127; int b = (i >> 7) & 255; int t = i >> 15;
  xG[i] = xs_pre[(b * T_ + t) * D_ + d];
}

// ===== Entire GRU scan in ONE launch =====
// 64 blocks x 1024 threads; block owns 4 batch cols; 128 time steps in-kernel.
// thread: bq = tid>>8 (0..3), ks = (tid>>6)&3 (split-K), lane = tid&63 (jj-group = lane*4)
__global__ __launch_bounds__(1024) void k_gru_all(
    const float* __restrict__ xG, const float* __restrict__ WihT,
    const float* __restrict__ WhhT, const float* __restrict__ bih,
    const float* __restrict__ bhh, float* __restrict__ hsT){
  int tid = threadIdx.x;
  int bq = tid >> 8;
  int ks = (tid >> 6) & 3;
  int lane = tid & 63;
  int b0 = blockIdx.x * 4;

  __shared__ float h_s[4][256];
  __shared__ float x_s[4][128];
  __shared__ float part[4][4][4][256];  // [bq][ch:r,z,nx,nh][ks][jj]  64 KB

  h_s[tid >> 8][tid & 255] = 0.f;

  for (int k = 0; k < T_; ++k){
    int t = 127 - k;
    __syncthreads();
    if (tid < 512){
      int ib = tid >> 7, d = tid & 127;
      x_s[ib][d] = xG[(t*256 + b0 + ib)*128 + d];
    }
    __syncthreads();

    float a0x=0,a0y=0,a0z=0,a0w=0;   // r (x+h)
    float a1x=0,a1y=0,a1z=0,a1w=0;   // z (x+h)
    float a2x=0,a2y=0,a2z=0,a2w=0;   // n from x
    float a3x=0,a3y=0,a3z=0,a3w=0;   // n from h
    int j4 = lane * 4;
    #pragma unroll 2
    for (int d = ks*32; d < ks*32 + 32; ++d){
      float xv = x_s[bq][d];
      const float* wr = WihT + d*768;
      float4 w0 = *(const float4*)(wr + j4);
      float4 w1 = *(const float4*)(wr + 256 + j4);
      float4 w2 = *(const float4*)(wr + 512 + j4);
      a0x=fmaf(xv,w0.x,a0x); a0y=fmaf(xv,w0.y,a0y); a0z=fmaf(xv,w0.z,a0z); a0w=fmaf(xv,w0.w,a0w);
      a1x=fmaf(xv,w1.x,a1x); a1y=fmaf(xv,w1.y,a1y); a1z=fmaf(xv,w1.z,a1z); a1w=fmaf(xv,w1.w,a1w);
      a2x=fmaf(xv,w2.x,a2x); a2y=fmaf(xv,w2.y,a2y); a2z=fmaf(xv,w2.z,a2z); a2w=fmaf(xv,w2.w,a2w);
    }
    #pragma unroll 2
    for (int kk = ks*64; kk < ks*64 + 64; ++kk){
      float hv = h_s[bq][kk];
      const float* wr = WhhT + kk*768;
      float4 w0 = *(const float4*)(wr + j4);
      float4 w1 = *(const float4*)(wr + 256 + j4);
      float4 w2 = *(const float4*)(wr + 512 + j4);
      a0x=fmaf(hv,w0.x,a0x); a0y=fmaf(hv,w0.y,a0y); a0z=fmaf(hv,w0.z,a0z); a0w=fmaf(hv,w0.w,a0w);
      a1x=fmaf(hv,w1.x,a1x); a1y=fmaf(hv,w1.y,a1y); a1z=fmaf(hv,w1.z,a1z); a1w=fmaf(hv,w1.w,a1w);
      a3x=fmaf(hv,w2.x,a3x); a3y=fmaf(hv,w2.y,a3y); a3z=fmaf(hv,w2.z,a3z); a3w=fmaf(hv,w2.w,a3w);
    }
    *(float4*)&part[bq][0][ks][j4] = make_float4(a0x,a0y,a0z,a0w);
    *(float4*)&part[bq][1][ks][j4] = make_float4(a1x,a1y,a1z,a1w);
    *(float4*)&part[bq][2][ks][j4] = make_float4(a2x,a2y,a2z,a2w);
    *(float4*)&part[bq][3][ks][j4] = make_float4(a3x,a3y,a3z,a3w);
    __syncthreads();
    {
      int bq2 = tid >> 8, jj = tid & 255;
      float s0 = part[bq2][0][0][jj] + part[bq2][0][1][jj] + part[bq2][0][2][jj] + part[bq2][0][3][jj];
      float s1 = part[bq2][1][0][jj] + part[bq2][1][1][jj] + part[bq2][1][2][jj] + part[bq2][1][3][jj];
      float s2 = part[bq2][2][0][jj] + part[bq2][2][1][jj] + part[bq2][2][2][jj] + part[bq2][2][3][jj];
      float s3 = part[bq2][3][0][jj] + part[bq2][3][1][jj] + part[bq2][3][2][jj] + part[bq2][3][3][jj];
      float gr = s0 + bih[jj] + bhh[jj];
      float gz = s1 + bih[256 + jj] + bhh[256 + jj];
      float gnx = s2 + bih[512 + jj];
      float gnh = s3 + bhh[512 + jj];
      float rr = sig_(gr);
      float uu = sig_(gz);
      float nn = tanh_(gnx + rr * gnh);
      float hn = (1.f - uu) * nn + uu * h_s[bq2][jj];
      hsT[((size_t)k*256 + b0 + bq2)*256 + jj] = hn;
      h_s[bq2][jj] = hn;
    }
  }
}

// ctx2[t][b][c] = hs[127-t] @ encW^T + encb   (2048 blocks x 256)
__global__ __launch_bounds__(256) void k_ctx2(
    const float* __restrict__ hsT, const float* __restrict__ encWT,
    const float* __restrict__ encb, float* __restrict__ ctx2){
  int t = blockIdx.x >> 4;
  int b0 = (blockIdx.x & 15) * 16;
  int tid = threadIdx.x;
  __shared__ float h_s[16][256];
  int kk0 = 127 - t;
  for (int i = tid; i < 4096; i += 256){
    int rr = i >> 8, jj = i & 255;
    h_s[rr][jj] = hsT[((size_t)kk0*256 + b0 + rr)*256 + jj];
  }
  __syncthreads();
  float acc0=0, acc1=0, acc2=0, acc3=0;
  int c = tid & 63;
  int bq0 = tid >> 6;
  #pragma unroll 4
  for (int kk = 0; kk < 256; ++kk){
    float wv = encWT[kk*64 + c];
    acc0 = fmaf(h_s[bq0][kk],      wv, acc0);
    acc1 = fmaf(h_s[bq0 + 4][kk],  wv, acc1);
    acc2 = fmaf(h_s[bq0 + 8][kk],  wv, acc2);
    acc3 = fmaf(h_s[bq0 + 12][kk], wv, acc3);
  }
  float bv = encb[c];
  ctx2[(t*256 + b0 + bq0)*64 + c]      = acc0 + bv;
  ctx2[(t*256 + b0 + bq0 + 4)*64 + c]  = acc1 + bv;
  ctx2[(t*256 + b0 + bq0 + 8)*64 + c]  = acc2 + bv;
  ctx2[(t*256 + b0 + bq0 + 12)*64 + c] = acc3 + bv;
}

// q(z0) head + KL reduction (reads ctx2[0][b][c])
__global__ void k_qz0(const float* __restrict__ ctx2, const float* __restrict__ qW,
                      const float* __restrict__ qb, const float* __restrict__ pm,
                      const float* __restrict__ pls, float* __restrict__ qmT,
                      float* __restrict__ qlsT, double* __restrict__ kl_acc){
  int b = threadIdx.x; int l = blockIdx.x;
  const float* crow = ctx2 + b * 64;
  const float* wm = qW + l * C_;
  const float* ws2 = qW + (L_ + l) * C_;
  float am = qb[l], as = qb[L_ + l];
  for (int c = 0; c < C_; ++c){
    float cv = crow[c];
    am = fmaf(cv, wm[c], am);
    as = fmaf(cv, ws2[c], as);
  }
  qmT[l * B_ + b] = am; qlsT[l * B_ + b] = as;
  float plsl = pls[l], pml = pm[l];
  float dm = am - pml;
  float kl = plsl - as + (__expf(2.f * as) + dm * dm) / (2.f * __expf(2.f * plsl)) - 0.5f;
  blk_reduce_add(kl, kl_acc);
}

// z0 -> zs[:, :, 0, :]
__global__ void k_z0(const float* __restrict__ eps0, const float* __restrict__ qmT,
                     const float* __restrict__ qlsT, float* __restrict__ zs){
  int r = blockIdx.x * 256 + threadIdx.x;
  int b = r & 255;
  for (int l = 0; l < L_; ++l){
    float z = fmaf(__expf(qlsT[l * B_ + b]), eps0[r * L_ + l], qmT[l * B_ + b]);
    zs[(size_t)r * (T_ * L_) + l] = z;
  }
}

// ===== Entire SDE Euler scan in ONE launch =====
// 256 blocks x 512 threads; block owns 16 rows; 127 steps in-kernel.
// matmul phases: rp = tid>>6 (rows rp, rp+8), g4 = (tid>>5)&1, lane = tid&31, j = g4*128+lane*4
// scalar phases: row16 = tid>>5, l = lane
__global__ __launch_bounds__(512) void k_sde_all(
    const float* __restrict__ ctx2,
    const float* __restrict__ fW1T, const float* __restrict__ fb1,
    const float* __restrict__ hW1T, const float* __restrict__ hb1,
    const float* __restrict__ fW2T, const float* __restrict__ fb2,
    const float* __restrict__ hW2T, const float* __restrict__ hb2,
    const float* __restrict__ fW3T, const float* __restrict__ fb3,
    const float* __restrict__ hW3T, const float* __restrict__ hb3,
    const float* __restrict__ gW1T, const float* __restrict__ gb1T,
    const float* __restrict__ gW2T, const float* __restrict__ gb2,
    const float* __restrict__ dW, float* __restrict__ zs,
    double* __restrict__ u2_acc){
  int tid = threadIdx.x;
  int r0 = blockIdx.x * 16;
  int b0 = r0 & 255;
  int rp = tid >> 6;
  int g4 = (tid >> 5) & 1;
  int lane = tid & 31;
  int row16 = tid >> 5;
  int jbase = g4 * 128 + lane * 4;

  __shared__ float z_s[16][32];
  __shared__ float ctx_s[16][64];
  __shared__ float a1_s[2][16][256];
  __shared__ float a2_s[2][16][256];
  __shared__ float fh_s[2][16][32];

  z_s[row16][lane] = zs[(size_t)(r0 + row16) * 4096 + lane];  // t=0
  float u2loc = 0.f;

  for (int k = 0; k < NT_; ++k){
    int tctx = k + 1;   // min(k+1,127) never binds for k<127
    __syncthreads();
    if (tid < 256){
      int rr = tid >> 4, c4 = (tid & 15) * 4;
      *(float4*)&ctx_s[rr][c4] = *(const float4*)(ctx2 + (tctx*256 + b0 + rr)*64 + c4);
    }
    __syncthreads();

    // ---------- L1: f (z,ctx -> 256) and h (z -> 256), softplus ----------
    {
      float aA0=0,aA1=0,aA2=0,aA3=0, aB0=0,aB1=0,aB2=0,aB3=0;
      #pragma unroll 4
      for (int kk = 0; kk < 32; ++kk){
        float vA = z_s[rp][kk], vB = z_s[rp + 8][kk];
        float4 w = *(const float4*)(fW1T + kk*256 + jbase);
        aA0=fmaf(vA,w.x,aA0); aA1=fmaf(vA,w.y,aA1); aA2=fmaf(vA,w.z,aA2); aA3=fmaf(vA,w.w,aA3);
        aB0=fmaf(vB,w.x,aB0); aB1=fmaf(vB,w.y,aB1); aB2=fmaf(vB,w.z,aB2); aB3=fmaf(vB,w.w,aB3);
      }
      #pragma unroll 4
      for (int kk = 0; kk < 64; ++kk){
        float vA = ctx_s[rp][kk], vB = ctx_s[rp + 8][kk];
        float4 w = *(const float4*)(fW1T + (32 + kk)*256 + jbase);
        aA0=fmaf(vA,w.x,aA0); aA1=fmaf(vA,w.y,aA1); aA2=fmaf(vA,w.z,aA2); aA3=fmaf(vA,w.w,aA3);
        aB0=fmaf(vB,w.x,aB0); aB1=fmaf(vB,w.y,aB1); aB2=fmaf(vB,w.z,aB2); aB3=fmaf(vB,w.w,aB3);
      }
      float4 bb = *(const float4*)(fb1 + jbase);
      *(float4*)&a1_s[0][rp][jbase]     = make_float4(sp_(aA0+bb.x), sp_(aA1+bb.y), sp_(aA2+bb.z), sp_(aA3+bb.w));
      *(float4*)&a1_s[0][rp + 8][jbase] = make_float4(sp_(aB0+bb.x), sp_(aB1+bb.y), sp_(aB2+bb.z), sp_(aB3+bb.w));

      aA0=0;aA1=0;aA2=0;aA3=0; aB0=0;aB1=0;aB2=0;aB3=0;
      #pragma unroll 4
      for (int kk = 0; kk < 32; ++kk){
        float vA = z_s[rp][kk], vB = z_s[rp + 8][kk];
        float4 w = *(const float4*)(hW1T + kk*256 + jbase);
        aA0=fmaf(vA,w.x,aA0); aA1=fmaf(vA,w.y,aA1); aA2=fmaf(vA,w.z,aA2); aA3=fmaf(vA,w.w,aA3);
        aB0=fmaf(vB,w.x,aB0); aB1=fmaf(vB,w.y,aB1); aB2=fmaf(vB,w.z,aB2); aB3=fmaf(vB,w.w,aB3);
      }
      float4 b2 = *(const float4*)(hb1 + jbase);
      *(float4*)&a1_s[1][rp][jbase]     = make_float4(sp_(aA0+b2.x), sp_(aA1+b2.y), sp_(aA2+b2.z), sp_(aA3+b2.w));
      *(float4*)&a1_s[1][rp + 8][jbase] = make_float4(sp_(aB0+b2.x), sp_(aB1+b2.y), sp_(aB2+b2.z), sp_(aB3+b2.w));
    }
    __syncthreads();

    // ---------- L2: f and h 256x256, softplus ----------
    {
      float aA0=0,aA1=0,aA2=0,aA3=0, aB0=0,aB1=0,aB2=0,aB3=0;
      #pragma unroll 4
      for (int kk = 0; kk < 256; ++kk){
        float vA = a1_s[0][rp][kk], vB = a1_s[0][rp + 8][kk];
        float4 w = *(const float4*)(fW2T + kk*256 + jbase);
        aA0=fmaf(vA,w.x,aA0); aA1=fmaf(vA,w.y,aA1); aA2=fmaf(vA,w.z,aA2); aA3=fmaf(vA,w.w,aA3);
        aB0=fmaf(vB,w.x,aB0); aB1=fmaf(vB,w.y,aB1); aB2=fmaf(vB,w.z,aB2); aB3=fmaf(vB,w.w,aB3);
      }
      float4 bb = *(const float4*)(fb2 + jbase);
      float4 oA = make_float4(sp_(aA0+bb.x), sp_(aA1+bb.y), sp_(aA2+bb.z), sp_(aA3+bb.w));
      float4 oB = make_float4(sp_(aB0+bb.x), sp_(aB1+bb.y), sp_(aB2+bb.z), sp_(aB3+bb.w));

      aA0=0;aA1=0;aA2=0;aA3=0; aB0=0;aB1=0;aB2=0;aB3=0;
      #pragma unroll 4
      for (int kk = 0; kk < 256; ++kk){
        float vA = a1_s[1][rp][kk], vB = a1_s[1][rp + 8][kk];
        float4 w = *(const float4*)(hW2T + kk*256 + jbase);
        aA0=fmaf(vA,w.x,aA0); aA1=fmaf(vA,w.y,aA1); aA2=fmaf(vA,w.z,aA2); aA3=fmaf(vA,w.w,aA3);
        aB0=fmaf(vB,w.x,aB0); aB1=fmaf(vB,w.y,aB1); aB2=fmaf(vB,w.z,aB2); aB3=fmaf(vB,w.w,aB3);
      }
      float4 b2 = *(const float4*)(hb2 + jbase);
      // write f first then h (no overlap of storage)
      *(float4*)&a2_s[0][rp][jbase]     = oA;
      *(float4*)&a2_s[0][rp + 8][jbase] = oB;
      *(float4*)&a2_s[1][rp][jbase]     = make_float4(sp_(aA0+b2.x), sp_(aA1+b2.y), sp_(aA2+b2.z), sp_(aA3+b2.w));
      *(float4*)&a2_s[1][rp + 8][jbase] = make_float4(sp_(aB0+b2.x), sp_(aB1+b2.y), sp_(aB2+b2.z), sp_(aB3+b2.w));
    }
    __syncthreads();

    // ---------- L3: net = g4, j = lane ----------
    {
      const float* w3 = g4 ? hW3T : fW3T;
      float sA = 0.f, sB = 0.f;
      #pragma unroll 4
      for (int kk = 0; kk < 256; ++kk){
        float wv = w3[kk*32 + lane];
        sA = fmaf(a2_s[g4][rp][kk],     wv, sA);
        sB = fmaf(a2_s[g4][rp + 8][kk], wv, sB);
      }
      float b3 = g4 ? hb3[lane] : fb3[lane];
      fh_s[g4][rp][lane]     = sA + b3;
      fh_s[g4][rp + 8][lane] = sB + b3;
    }
    __syncthreads();

    // ---------- diagonal g-net + Euler update + logqp ----------
    {
      float zl = z_s[row16][lane];
      float gacc = 0.f;
      #pragma unroll 4
      for (int h = 0; h < 256; ++h){
        float xg = fmaf(zl, gW1T[h*32 + lane], gb1T[h*32 + lane]);
        gacc = fmaf(sp_(xg), gW2T[h*32 + lane], gacc);
      }
      float gv = sig_(gacc + gb2[lane]) + 0.01f;
      float fv = fh_s[0][row16][lane];
      float hv = fh_s[1][row16][lane];
      float uu = (fv - hv) / gv;
      u2loc = fmaf(uu, uu, u2loc);
      int r = r0 + row16;
      float dwv = dW[((size_t)k*4096 + r)*32 + lane];
      float zn = zl + fv*DT + gv*(SQDT*dwv);
      z_s[row16][lane] = zn;   // safe: only this thread touches (row16,lane); all cross-reads done
      zs[((size_t)r*128 + (k + 1))*32 + lane] = zn;
    }
  }

  // block reduction of u2loc (512 threads)
  for (int o = 32; o > 0; o >>= 1) u2loc += __shfl_down(u2loc, o, 64);
  __shared__ float wp[8];
  if ((tid & 63) == 0) wp[tid >> 6] = u2loc;
  __syncthreads();
  if (tid == 0){
    float s = 0.f;
    #pragma unroll
    for (int q = 0; q < 8; ++q) s += wp[q];
    atomicAdd(u2_acc, (double)s);
  }
}

// Poisson log-likelihood: grid-stride, one atomic per block
__global__ void k_pois(const float* __restrict__ zs, const float* __restrict__ Cw,
                       const float* __restrict__ db, const float* __restrict__ xs_pre,
                       double* __restrict__ ell_acc){
  const int N = S_ * B_ * T_ * D_;
  const int stride = 4096 * 256;
  float local = 0.f;
  for (int i = blockIdx.x * 256 + threadIdx.x; i < N; i += stride){
    int d = i & 127; int row = i >> 7;
    int t = row & 127; int b = (row >> 7) & 255;
    const float* zrow = zs + (size_t)row * L_;
    float lr = db[d] - 3.912023005428146f;
    #pragma unroll 8
    for (int l = 0; l < L_; ++l) lr = fmaf(zrow[l], Cw[l * D_ + d], lr);
    float xv = xs_pre[(b * T_ + t) * D_ + d];
    int xi = (int)(xv + 0.5f);
    float lg = (xi <= 1) ? 0.f : (xi == 2 ? 0.6931471805599453f :
               (xi == 3 ? 1.791759469228055f : 3.1780538303479458f));
    local += xv * lr - __expf(lr) - lg;
  }
  blk_reduce_add(local, ell_acc);
}

// mean and unbiased variance over S
__global__ void k_mv(const float* __restrict__ zs, float* __restrict__ m, float* __restrict__ P){
  int i = blockIdx.x * 256 + threadIdx.x;
  float x[S_];
  float s = 0.f;
  #pragma unroll
  for (int q = 0; q < S_; ++q){ x[q] = zs[(size_t)q * (B_ * T_ * L_) + i]; s += x[q]; }
  float mu = s * (1.f / S_);
  float v = 0.f;
  #pragma unroll
  for (int q = 0; q < S_; ++q){ float dd = x[q] - mu; v = fmaf(dd, dd, v); }
  m[i] = mu;
  P[i] = v * (1.f / (S_ - 1));
}

__global__ void k_fin(const double* __restrict__ accs, float* __restrict__ out){
  double log_pxs = accs[0] / 4096.0;
  double logqp0 = accs[1] / 256.0;
  double logqp_path = 0.5 * 0.02 * accs[2] / 4096.0;
  out[0] = (float)(-log_pxs + logqp0 + logqp_path);
}

extern "C" void kernel_launch(void* const* d_in, const int* in_sizes, int n_in,
                              void* d_out, int out_size, void* d_ws, size_t ws_size,
                              hipStream_t stream) {
  const float* xs_pre = (const float*)d_in[0];
  const float* eps0   = (const float*)d_in[1];
  const float* dW     = (const float*)d_in[2];
  const float* Wih    = (const float*)d_in[3];
  const float* Whh    = (const float*)d_in[4];
  const float* bih    = (const float*)d_in[5];
  const float* bhh    = (const float*)d_in[6];
  const float* encW   = (const float*)d_in[7];
  const float* encb   = (const float*)d_in[8];
  const float* qW     = (const float*)d_in[9];
  const float* qb     = (const float*)d_in[10];
  const float* fW1    = (const float*)d_in[11];
  const float* fb1    = (const float*)d_in[12];
  const float* fW2    = (const float*)d_in[13];
  const float* fb2    = (const float*)d_in[14];
  const float* fW3    = (const float*)d_in[15];
  const float* fb3    = (const float*)d_in[16];
  const float* hW1    = (const float*)d_in[17];
  const float* hb1    = (const float*)d_in[18];
  const float* hW2    = (const float*)d_in[19];
  const float* hb2    = (const float*)d_in[20];
  const float* hW3    = (const float*)d_in[21];
  const float* hb3    = (const float*)d_in[22];
  const float* gW1    = (const float*)d_in[23];
  const float* gb1    = (const float*)d_in[24];
  const float* gW2    = (const float*)d_in[25];
  const float* gb2    = (const float*)d_in[26];
  const float* pm     = (const float*)d_in[27];
  const float* pls    = (const float*)d_in[28];
  const float* Cw     = (const float*)d_in[29];
  const float* db     = (const float*)d_in[30];

  float* out = (float*)d_out;
  float* zs  = out + 1;                      // (S,B,T,L)
  float* m   = out + 1 + 16777216;           // (B,T,L)
  float* P   = m + 1048576;

  // workspace layout (floats from +16; accs = 3 doubles at base)
  double* accs = (double*)d_ws;
  float* wf = (float*)d_ws + 16;
  float* xG    = wf; wf += T_ * B_ * D_;     // 4,194,304
  float* hsT   = wf; wf += T_ * B_ * H_;     // 8,388,608  [k][b][jj]
  float* ctx2  = wf; wf += T_ * B_ * C_;     // 2,097,152  [t][b][c]
  float* WihT  = wf; wf += 98304;
  float* WhhT  = wf; wf += 196608;
  float* encWT = wf; wf += 16384;
  float* fW1T  = wf; wf += 24576;
  float* hW1T  = wf; wf += 8192;
  float* fW2T  = wf; wf += 65536;
  float* hW2T  = wf; wf += 65536;
  float* fW3T  = wf; wf += 8192;
  float* hW3T  = wf; wf += 8192;
  float* gW1T  = wf; wf += 8192;
  float* gb1T  = wf; wf += 8192;
  float* gW2T  = wf; wf += 8192;
  float* qmT   = wf; wf += 8192;
  float* qlsT  = wf; wf += 8192;
  size_t need = (size_t)(wf - (float*)d_ws) * 4;
  if (ws_size < need) return;

  k_init<<<1, 64, 0, stream>>>(accs);
  k_prep<<<2016, 256, 0, stream>>>(Wih, Whh, encW, fW1, hW1, fW2, hW2, fW3, hW3,
                                   gW1, gb1, gW2,
                                   WihT, WhhT, encWT, fW1T, hW1T, fW2T, hW2T,
                                   fW3T, hW3T, gW1T, gb1T, gW2T);
  k_xg<<<16384, 256, 0, stream>>>(xs_pre, xG);
  k_gru_all<<<64, 1024, 0, stream>>>(xG, WihT, WhhT, bih, bhh, hsT);
  k_ctx2<<<2048, 256, 0, stream>>>(hsT, encWT, encb, ctx2);
  k_qz0<<<32, 256, 0, stream>>>(ctx2, qW, qb, pm, pls, qmT, qlsT, accs + 1);
  k_z0<<<16, 256, 0, stream>>>(eps0, qmT, qlsT, zs);
  k_sde_all<<<256, 512, 0, stream>>>(ctx2,
                                     fW1T, fb1, hW1T, hb1,
                                     fW2T, fb2, hW2T, hb2,
                                     fW3T, fb3, hW3T, hb3,
                                     gW1T, gb1T, gW2T, gb2,
                                     dW, zs, accs + 2);
  k_pois<<<4096, 256, 0, stream>>>(zs, Cw, db, xs_pre, accs + 0);
  k_mv<<<4096, 256, 0, stream>>>(zs, m, P);
  k_fin<<<1, 1, 0, stream>>>(accs, out);
}